// Round 7
// baseline (924.971 us; speedup 1.0000x reference)
//
#include <hip/hip_runtime.h>

// ============================================================================
// Djpegnet round 7.
//  - conv5_mfma restructured: 256-thread blocks, BLK_M=64, grids >=512 so TWO
//    independent blocks/CU co-reside (VGPR budget 232/wave = 2 waves/SIMD =
//    8 waves/CU; round-6's single 512-thr block left barriers uncovered).
//  - Double-buffered Wlds with async global_load_lds prefetch: chunk c+1's
//    weight copies + A register loads issued right after the staging barrier,
//    flying under chunk c's compute.
//  - kw-packed 26-col weight layout (no stored zero kw=5 col; A-operand
//    register zeroed via select for kwb==2,hi==1 lanes) -> Wlds 26.6KB,
//    2xWlds + Alds <= 67KB -> 2 blocks/CU by LDS too.
//  - conv3a HC 20->24 (row stride 384B, 128B-aligned) -> kills the 7.86M
//    LDS bank conflicts unique to W=16.
//  - Fused BN+ReLU+maxpool epilogue, grouped-f16 activations, fc1 MFMA
//    split-K: unchanged from round 6.
// ============================================================================

typedef _Float16 half8 __attribute__((ext_vector_type(8)));
typedef _Float16 half4 __attribute__((ext_vector_type(4)));
typedef float f32x16 __attribute__((ext_vector_type(16)));

__device__ __forceinline__ void async_copy16(const void* g, void* l) {
  __builtin_amdgcn_global_load_lds(
      (__attribute__((address_space(1))) void*)g,
      (__attribute__((address_space(3))) void*)l, 16, 0, 0);
}

// ---------------------------------------------------------------- DCT ------
__global__ __launch_bounds__(256) void dct_kernel(const float* __restrict__ x,
                                                  const float* __restrict__ basis,
                                                  float* __restrict__ dct) {
  __shared__ __align__(16) float Bm[64];
  int tid = threadIdx.x;
  if (tid < 64) {
    int u = tid >> 3, xx = tid & 7;
    Bm[tid] = basis[(u * 8) * 64 + xx * 8] * 2.8284271247461903f;
  }
  __syncthreads();
  int gid = blockIdx.x * 256 + tid;
  int b = gid >> 10, blk = gid & 1023;
  int bi = blk >> 5, bj = blk & 31;
  const float* xp = x + (size_t)b * 65536 + (bi * 8) * 256 + bj * 8;
  float X[64];
#pragma unroll
  for (int r = 0; r < 8; ++r) {
    float4 p = *(const float4*)(xp + r * 256);
    float4 q = *(const float4*)(xp + r * 256 + 4);
    X[r * 8 + 0] = p.x; X[r * 8 + 1] = p.y; X[r * 8 + 2] = p.z; X[r * 8 + 3] = p.w;
    X[r * 8 + 4] = q.x; X[r * 8 + 5] = q.y; X[r * 8 + 6] = q.z; X[r * 8 + 7] = q.w;
  }
  float T[64];
#pragma unroll
  for (int u = 0; u < 8; ++u) {
    float t[8] = {0.f, 0.f, 0.f, 0.f, 0.f, 0.f, 0.f, 0.f};
#pragma unroll
    for (int xx = 0; xx < 8; ++xx) {
      float bm = Bm[u * 8 + xx];
#pragma unroll
      for (int y = 0; y < 8; ++y) t[y] += bm * X[xx * 8 + y];
    }
#pragma unroll
    for (int y = 0; y < 8; ++y) T[u * 8 + y] = t[y];
  }
  float* op = dct + (size_t)b * 65536 + bi * 32 + bj;
#pragma unroll
  for (int v = 0; v < 8; ++v) {
    float dc[8] = {0.f, 0.f, 0.f, 0.f, 0.f, 0.f, 0.f, 0.f};
#pragma unroll
    for (int y = 0; y < 8; ++y) {
      float bm = Bm[v * 8 + y];
#pragma unroll
      for (int u = 0; u < 8; ++u) dc[u] += bm * T[u * 8 + y];
    }
#pragma unroll
    for (int u = 0; u < 8; ++u) op[(u * 8 + v) * 1024] = dc[u];
  }
}

// ---------------------------------------------------- soft histogram -------
__global__ __launch_bounds__(256) void hist_kernel(const float* __restrict__ dct,
                                                   float* __restrict__ feat) {
  __shared__ __align__(16) float h[16 * 121];
  int tid = threadIdx.x;
  for (int i = tid; i < 16 * 121; i += 256) h[i] = 0.f;
  __syncthreads();
  int b = blockIdx.x >> 6, c = blockIdx.x & 63;
  const float* dp = dct + (size_t)(b * 64 + c) * 1024;
  float* hc = h + (tid & 15) * 121;
  float4 v4 = ((const float4*)dp)[tid];
  float vals[4] = {v4.x, v4.y, v4.z, v4.w};
#pragma unroll
  for (int i = 0; i < 4; ++i) {
    float d = vals[i];
    float fl = floorf(d);
    float t0 = d - fl;
    int k = (int)fl + 60;
    if (t0 >= 2e-5f && t0 <= 1.f - 1.2e-4f) {
      if (k >= 0 && k < 120) atomicAdd(hc + k, 1.0f);
    } else {
      float s0 = 1.f / (1.f + expf(-1e6f * t0));
      float s1 = 1.f / (1.f + expf(1e6f * (1.f - t0)));
      if (k >= 1 && k <= 120) atomicAdd(hc + k - 1, 1.f - s0);
      if (k >= 0 && k < 120)  atomicAdd(hc + k, s0 - s1);
      if (k >= -1 && k < 119) atomicAdd(hc + k + 1, s1);
    }
  }
  __syncthreads();
  for (int f = tid; f < 120; f += 256) {
    float s = 0.f;
#pragma unroll
    for (int l = 0; l < 16; ++l) s += h[l * 121 + f];
    feat[((size_t)b * 120 + f) * 64 + c] = s * (1.f / 1024.f);
  }
}

// ---------------------------------------- weight transpose + BN folding ----
// wt layout: [cg][26][co][8ci], col = kh*5+kw (kw 0..4); col 25 = zeros.
template <int CI, int CO>
__global__ __launch_bounds__(256) void wtrans(const float* __restrict__ w,
                                              _Float16* __restrict__ wt) {
  int i = blockIdx.x * 256 + threadIdx.x;
  if (i >= (CI / 8) * 26 * CO * 8) return;
  int c8 = i & 7;
  int t = i >> 3;
  int co = t % CO; t /= CO;
  int k = t % 26;
  int cg = t / 26;
  float v = 0.f;
  if (k < 25) {
    int kh = k / 5, kw = k % 5;
    v = w[((size_t)co * CI + cg * 8 + c8) * 25 + kh * 5 + kw];
  }
  wt[i] = (_Float16)v;
}

__global__ __launch_bounds__(256) void bnprep(const float* __restrict__ cb,
                                              const float* __restrict__ s,
                                              const float* __restrict__ b,
                                              const float* __restrict__ m,
                                              const float* __restrict__ v,
                                              float* __restrict__ scale,
                                              float* __restrict__ shift, int n) {
  int i = threadIdx.x;
  if (i < n) {
    float inv = s[i] * rsqrtf(v[i] + 1e-5f);
    scale[i] = inv;
    shift[i] = (cb[i] - m[i]) * inv + b[i];
  }
}

// -------------------------- conv1a: fp32 direct, out grouped-NHWC f16 ------
__global__ __launch_bounds__(256) void conv1a_f16(
    const float* __restrict__ in, const float* __restrict__ wts,
    const float* __restrict__ cb, const float* __restrict__ s_,
    const float* __restrict__ b_, const float* __restrict__ m_,
    const float* __restrict__ v_, _Float16* __restrict__ out) {
  __shared__ __align__(16) float wl[5 * 8 * 20];
  __shared__ __align__(16) float il[12 * 68];
  int tid = threadIdx.x, bid = blockIdx.x;
  int img = bid / 30;
  int r = bid % 30;
  int cob = r / 15;
  int h0 = (r % 15) * 8;
  int cog = tid & 7, wg = (tid >> 3) & 3, hh = tid >> 5;
  float acc[4][16];
#pragma unroll
  for (int i = 0; i < 4; ++i)
#pragma unroll
    for (int j = 0; j < 16; ++j) acc[i][j] = 0.f;
  for (int idx = tid; idx < 32 * 25; idx += 256) {
    int rr = idx % 25, co = idx / 25;
    float v = wts[(cob * 32 + co) * 25 + rr];
    int kh = rr / 5, kw = rr % 5;
    wl[(kh * 8 + (co >> 2)) * 20 + (co & 3) * 5 + kw] = v;
  }
  for (int idx = tid; idx < 12 * 68; idx += 256) {
    int cc = idx % 68, rr = idx / 68;
    int hy = h0 + rr - 2, wx = cc - 2;
    float v = 0.f;
    if (hy >= 0 && hy < 120 && wx >= 0 && wx < 64)
      v = in[(size_t)img * 7680 + hy * 64 + wx];
    il[idx] = v;
  }
  __syncthreads();
#pragma unroll
  for (int kh = 0; kh < 5; ++kh) {
    const float* ir = &il[(hh + kh) * 68 + wg * 16];
    float iv[20];
#pragma unroll
    for (int i = 0; i < 5; ++i) {
      float4 p = *(const float4*)(ir + i * 4);
      iv[i * 4] = p.x; iv[i * 4 + 1] = p.y; iv[i * 4 + 2] = p.z; iv[i * 4 + 3] = p.w;
    }
    const float* wr = &wl[(kh * 8 + cog) * 20];
    float wv[20];
#pragma unroll
    for (int i = 0; i < 5; ++i) {
      float4 p = *(const float4*)(wr + i * 4);
      wv[i * 4] = p.x; wv[i * 4 + 1] = p.y; wv[i * 4 + 2] = p.z; wv[i * 4 + 3] = p.w;
    }
#pragma unroll
    for (int co = 0; co < 4; ++co)
#pragma unroll
      for (int kw = 0; kw < 5; ++kw) {
        float w1 = wv[co * 5 + kw];
#pragma unroll
        for (int w = 0; w < 16; ++w) acc[co][w] += w1 * iv[w + kw];
      }
  }
  int h = h0 + hh;
  int co0 = cob * 32 + cog * 4;
  float inv[4], bia[4];
#pragma unroll
  for (int i = 0; i < 4; ++i) {
    int c = co0 + i;
    inv[i] = s_[c] * rsqrtf(v_[c] + 1e-5f);
    bia[i] = (cb[c] - m_[c]) * inv[i] + b_[c];
  }
  int g = co0 >> 3, off = co0 & 7;
  _Float16* op = out + (((size_t)(img * 8 + g) * 120 + h) * 64) * 8 + off;
#pragma unroll
  for (int w = 0; w < 16; ++w) {
    half4 o;
#pragma unroll
    for (int i = 0; i < 4; ++i)
      o[i] = (_Float16)fmaxf(acc[i][w] * inv[i] + bia[i], 0.f);
    *(half4*)&op[(size_t)(wg * 16 + w) * 8] = o;
  }
}

// ------ MFMA implicit-GEMM 5x5 conv + BN + ReLU + maxpool2 (pipelined) -----
// 256 threads / 4 waves, BLK_M=64. Wlds double-buffered + async prefetch.
// Output pooled: grouped [img][CO/8][H/2][W/2][8] or NCHW [img][CO][H/2][W/2].
template <int CI, int CO, int H, int W, int BLK_M, bool OUT_NCHW>
__global__ __launch_bounds__(256) void conv5_mfma(
    const _Float16* __restrict__ in, const _Float16* __restrict__ wt,
    const float* __restrict__ scale, const float* __restrict__ shift,
    _Float16* __restrict__ out) {
  constexpr int THREADS = 256;
  constexpr int NW = THREADS / 64;
  constexpr int NW_M = BLK_M / 64;
  constexpr int NW_N = NW / NW_M;
  constexpr int BLK_N = NW_N * 128;
  constexpr int ROWS = BLK_N / W;
  constexpr int TB = (H + ROWS - 1) / ROWS;
  constexpr int NCOB = CO / BLK_M;
  constexpr int HR = ROWS + 4;
  constexpr int HC = (W == 16) ? 24 : (W + 4);  // pad W=16 rows to 384B (bank-align)
  constexpr int CIG = CI / 8;
  constexpr int OH = H / 2, OW = W / 2;
  constexpr int AITER = (HR * HC + THREADS - 1) / THREADS;
  constexpr int KCOLS = 26;                     // kh*5+kw packed, col 25 = zeros
  constexpr int WHALF = KCOLS * BLK_M * 8;
  constexpr int WBYTES = WHALF * 2;
  constexpr int WITER = (WBYTES + THREADS * 16 - 1) / (THREADS * 16);
  __shared__ __align__(16) _Float16 Alds[HR * HC * 8 + 8];
  __shared__ __align__(16) _Float16 Wlds[2][WHALF];

  int tid = threadIdx.x;
  int bid = blockIdx.x;
  int img = bid / (TB * NCOB);
  int r = bid % (TB * NCOB);
  int tb = r / NCOB;
  int cob = r % NCOB;
  int h0 = tb * ROWS;

  int wid = tid >> 6, l = tid & 63, lo = l & 31, hi = l >> 5;
  int widM = wid / NW_N, widN = wid % NW_N;

  if (tid < 8) Alds[HR * HC * 8 + tid] = (_Float16)0.f;  // zero read-slack

  int wbase[2];
#pragma unroll
  for (int mi = 0; mi < 2; ++mi)
    wbase[mi] = (hi * BLK_M + widM * 64 + mi * 32 + lo) * 8;
  int bbase[4];
#pragma unroll
  for (int j = 0; j < 4; ++j) {
    int pix = widN * 128 + j * 32 + lo;
    bbase[j] = ((pix / W) * HC + (pix % W) + hi) * 8;
  }

  const _Float16* inb = in + (size_t)(img * CIG) * H * W * 8;

  auto loadA = [&](int cg, half8* areg) {
    const _Float16* ing = inb + (size_t)cg * H * W * 8;
#pragma unroll
    for (int it = 0; it < AITER; ++it) {
      int i = tid + it * THREADS;
      half8 v = {};
      if (i < HR * HC) {
        int rr2 = i / HC, cc = i % HC;
        int hy = h0 + rr2 - 2, wx = cc - 2;
        if (hy >= 0 && hy < H && wx >= 0 && wx < W)
          v = *(const half8*)&ing[(size_t)(hy * W + wx) * 8];
      }
      areg[it] = v;
    }
  };
  auto issueW = [&](int cg, int pb) {
    const char* wsrc = (const char*)(wt + ((size_t)cg * KCOLS * CO + cob * BLK_M) * 8);
    char* wdst = (char*)&Wlds[pb][0];
#pragma unroll
    for (int rr2 = 0; rr2 < WITER; ++rr2) {
      int f = rr2 * (THREADS * 16) + tid * 16;
      if (f < WBYTES) {
        int row = f >> 10;           // /(BLK_M*16), BLK_M=64
        int off = f & 1023;
        async_copy16(wsrc + (size_t)row * (CO * 16) + off,
                     wdst + rr2 * (THREADS * 16) + wid * 1024);
      }
    }
  };

  f32x16 acc[2][4];
#pragma unroll
  for (int mi = 0; mi < 2; ++mi)
#pragma unroll
    for (int j = 0; j < 4; ++j) acc[mi][j] = (f32x16){};

  half8 areg[AITER];
  loadA(0, areg);
  issueW(0, 0);
  int p = 0;

#pragma unroll 1
  for (int cg = 0; cg < CIG; ++cg) {
#pragma unroll
    for (int it = 0; it < AITER; ++it) {
      int i = tid + it * THREADS;
      if (i < HR * HC) *(half8*)&Alds[i * 8] = areg[it];
    }
    __syncthreads();   // Wlds[p] arrived (vmcnt drain) + Alds written
    if (cg + 1 < CIG) {
      issueW(cg + 1, p ^ 1);   // flies under this chunk's compute
      loadA(cg + 1, areg);
    }
    const _Float16* Wp = &Wlds[p][0];
#pragma unroll
    for (int kh = 0; kh < 5; ++kh) {
#pragma unroll
      for (int kwb = 0; kwb < 3; ++kwb) {
        half8 af[2], bf[4];
#pragma unroll
        for (int mi = 0; mi < 2; ++mi) {
          af[mi] = *(const half8*)&Wp[wbase[mi] + (kh * 5 + 2 * kwb) * BLK_M * 8];
          if (kwb == 2) af[mi] = hi ? (half8){} : af[mi];  // packed kw=5 tap
        }
#pragma unroll
        for (int j = 0; j < 4; ++j)
          bf[j] = *(const half8*)&Alds[bbase[j] + (kh * HC + 2 * kwb) * 8];
#pragma unroll
        for (int mi = 0; mi < 2; ++mi)
#pragma unroll
          for (int j = 0; j < 4; ++j)
            acc[mi][j] = __builtin_amdgcn_mfma_f32_32x32x16_f16(
                af[mi], bf[j], acc[mi][j], 0, 0, 0);
      }
    }
    __syncthreads();   // Alds consumed; safe to overwrite next iter
    p ^= 1;
  }

  // ---- fused BN + ReLU + 2x2 maxpool epilogue ----
  if (!OUT_NCHW) {
    constexpr int CGO = CO / 8;
    int gbase = (cob * BLK_M + widM * 64) >> 3;
    bool lane_ok = ((lo & 1) == 0);
#pragma unroll
    for (int mi = 0; mi < 2; ++mi) {
#pragma unroll
      for (int r4 = 0; r4 < 4; ++r4) {
        int g = gbase + mi * 4 + r4;
        int co0 = g * 8 + hi * 4;
        float4 sv = *(const float4*)&scale[co0];
        float4 tv = *(const float4*)&shift[co0];
        float sa[4] = {sv.x, sv.y, sv.z, sv.w};
        float ta[4] = {tv.x, tv.y, tv.z, tv.w};
#pragma unroll
        for (int pp = 0; pp < 2; ++pp) {
          int ja = (W == 64) ? pp : 2 * pp;
          int jb = (W == 64) ? pp + 2 : 2 * pp + 1;
          int orow = (W == 64) ? (h0 >> 1) + widN : (h0 >> 1) + widN * 2 + pp;
          int ocol = (W == 64) ? pp * 16 + (lo >> 1) : (lo >> 1);
          half4 o;
#pragma unroll
          for (int c = 0; c < 4; ++c) {
            int reg = r4 * 4 + c;
            float v0 = fmaxf(acc[mi][ja][reg] * sa[c] + ta[c], 0.f);
            float v1 = fmaxf(acc[mi][jb][reg] * sa[c] + ta[c], 0.f);
            float m = fmaxf(v0, v1);
            m = fmaxf(m, __shfl_xor(m, 1, 64));
            o[c] = (_Float16)m;
          }
          if (lane_ok && orow < OH)
            *(half4*)&out[(((size_t)(img * CGO + g) * OH + orow) * OW + ocol) * 8 +
                          hi * 4] = o;
        }
      }
    }
  } else {
    bool lane_ok = ((lo & 1) == 0) && (lo < 16);
#pragma unroll
    for (int mi = 0; mi < 2; ++mi) {
#pragma unroll
      for (int reg = 0; reg < 16; ++reg) {
        int co = cob * BLK_M + widM * 64 + mi * 32 + (reg & 3) + 8 * (reg >> 2) + 4 * hi;
        float s = scale[co], t = shift[co];
#pragma unroll
        for (int j = 0; j < 4; ++j) {
          float v = fmaxf(acc[mi][j][reg] * s + t, 0.f);
          float m = fmaxf(v, __shfl_xor(v, 16, 64));
          m = fmaxf(m, __shfl_xor(m, 1, 64));
          int orow = (h0 >> 1) + widN * 4 + j;
          if (lane_ok && orow < OH)
            out[((size_t)(img * CO + co) * OH + orow) * OW + ((lo & 15) >> 1)] =
                (_Float16)m;
        }
      }
    }
  }
}

// --------------------------------------------------- fc1: f16 MFMA split-K -
__global__ __launch_bounds__(256, 2) void fc1_mfma(const float* __restrict__ qv,
                                                   const _Float16* __restrict__ p3,
                                                   const float* __restrict__ w,
                                                   float* __restrict__ part) {
  __shared__ __align__(16) _Float16 Wl[8 * 256 * 8];
  __shared__ __align__(16) _Float16 Bl[8 * 128 * 8];
  int tid = threadIdx.x;
  int ks = blockIdx.x >> 1, mt = blockIdx.x & 1;
  int wid = tid >> 6, l = tid & 63, lo = l & 31, hi = l >> 5;
  f32x16 acc[2][4];
#pragma unroll
  for (int mi = 0; mi < 2; ++mi)
#pragma unroll
    for (int j = 0; j < 4; ++j) acc[mi][j] = (f32x16){};

#pragma unroll 1
  for (int i3 = 0; i3 < 3; ++i3) {
    int c = ks + 240 * i3;
    if (c > 480) break;
    for (int idx = tid; idx < 2048; idx += 256) {
      int n_loc = idx >> 3, k8 = idx & 7;
      int n = mt * 256 + n_loc;
      half8 v = {};
      if (n < 500) {
        const float* src = w + (size_t)n * 30784 + c * 64 + k8 * 8;
        float4 f0 = *(const float4*)src;
        float4 f1 = *(const float4*)(src + 4);
        v[0] = (_Float16)f0.x; v[1] = (_Float16)f0.y;
        v[2] = (_Float16)f0.z; v[3] = (_Float16)f0.w;
        v[4] = (_Float16)f1.x; v[5] = (_Float16)f1.y;
        v[6] = (_Float16)f1.z; v[7] = (_Float16)f1.w;
      }
      *(half8*)&Wl[(size_t)(k8 * 256 + n_loc) * 8] = v;
    }
    for (int idx = tid; idx < 1024; idx += 256) {
      int img = idx >> 3, k8 = idx & 7;
      half8 v;
      if (c == 0) {
        const float* src = qv + img * 64 + k8 * 8;
        float4 f0 = *(const float4*)src;
        float4 f1 = *(const float4*)(src + 4);
        v[0] = (_Float16)f0.x; v[1] = (_Float16)f0.y;
        v[2] = (_Float16)f0.z; v[3] = (_Float16)f0.w;
        v[4] = (_Float16)f1.x; v[5] = (_Float16)f1.y;
        v[6] = (_Float16)f1.z; v[7] = (_Float16)f1.w;
      } else {
        v = *(const half8*)&p3[(size_t)img * 30720 + (c * 64 - 64) + k8 * 8];
      }
      *(half8*)&Bl[(size_t)(k8 * 128 + img) * 8] = v;
    }
    __syncthreads();
#pragma unroll
    for (int ks16 = 0; ks16 < 4; ++ks16) {
      half8 af[2], bf[4];
#pragma unroll
      for (int mi = 0; mi < 2; ++mi)
        af[mi] = *(const half8*)&Wl[(size_t)((ks16 * 2 + hi) * 256 + wid * 64 +
                                             mi * 32 + lo) * 8];
#pragma unroll
      for (int j = 0; j < 4; ++j)
        bf[j] = *(const half8*)&Bl[(size_t)((ks16 * 2 + hi) * 128 + j * 32 + lo) * 8];
#pragma unroll
      for (int mi = 0; mi < 2; ++mi)
#pragma unroll
        for (int j = 0; j < 4; ++j)
          acc[mi][j] = __builtin_amdgcn_mfma_f32_32x32x16_f16(
              af[mi], bf[j], acc[mi][j], 0, 0, 0);
    }
    __syncthreads();
  }
#pragma unroll
  for (int mi = 0; mi < 2; ++mi)
#pragma unroll
    for (int reg = 0; reg < 16; ++reg) {
      int n = mt * 256 + wid * 64 + mi * 32 + (reg & 3) + 8 * (reg >> 2) + 4 * hi;
#pragma unroll
      for (int j = 0; j < 4; ++j)
        part[((size_t)ks * 512 + n) * 128 + j * 32 + lo] = acc[mi][j][reg];
    }
}

__global__ __launch_bounds__(256) void fc1_reduce(const float* __restrict__ part,
                                                  const float* __restrict__ bias,
                                                  float* __restrict__ out) {
  int idx = blockIdx.x * 256 + threadIdx.x;
  int img = idx & 127, n = idx >> 7;
  float s = 0.f;
#pragma unroll 8
  for (int ks = 0; ks < 240; ++ks) s += part[((size_t)ks * 512 + n) * 128 + img];
  out[n * 128 + img] = (n < 500) ? fmaxf(s + bias[n], 0.f) : 0.f;
}

// -------------------------------------------------------- fc2 / fc3 --------
__global__ __launch_bounds__(256) void fc2_kernel(const float* __restrict__ qv,
                                                  const float* __restrict__ fc1o,
                                                  const float* __restrict__ w,
                                                  const float* __restrict__ bias,
                                                  float* __restrict__ out) {
  int idx = blockIdx.x * 256 + threadIdx.x;
  if (idx >= 128 * 500) return;
  int m = idx & 127, n = idx >> 7;
  const float* wr = w + (size_t)n * 564;
  float acc = 0.f;
#pragma unroll 8
  for (int k = 0; k < 64; ++k) acc += qv[m * 64 + k] * wr[k];
#pragma unroll 4
  for (int k = 0; k < 500; ++k) acc += fc1o[k * 128 + m] * wr[64 + k];
  out[n * 128 + m] = fmaxf(acc + bias[n], 0.f);
}

__global__ __launch_bounds__(256) void fc3_kernel(const float* __restrict__ qv,
                                                  const float* __restrict__ fc2o,
                                                  const float* __restrict__ w,
                                                  const float* __restrict__ bias,
                                                  float* __restrict__ out) {
  int tid = threadIdx.x;
  int m = tid >> 1, n = tid & 1;
  const float* wr = w + (size_t)n * 564;
  float acc = 0.f;
#pragma unroll 8
  for (int k = 0; k < 64; ++k) acc += qv[m * 64 + k] * wr[k];
#pragma unroll 4
  for (int k = 0; k < 500; ++k) acc += fc2o[k * 128 + m] * wr[64 + k];
  out[m * 2 + n] = acc + bias[n];
}

// ----------------------------------------------------------- launcher ------
extern "C" void kernel_launch(void* const* d_in, const int* in_sizes, int n_in,
                              void* d_out, int out_size, void* d_ws, size_t ws_size,
                              hipStream_t stream) {
  (void)in_sizes; (void)n_in; (void)out_size; (void)ws_size;
  const float* x      = (const float*)d_in[0];
  const float* qv     = (const float*)d_in[1];
  const float* basis  = (const float*)d_in[2];
  const float* c1aw   = (const float*)d_in[3];
  const float* c1ab   = (const float*)d_in[4];
  const float* c1bw   = (const float*)d_in[5];
  const float* c1bb   = (const float*)d_in[6];
  const float* c2aw   = (const float*)d_in[7];
  const float* c2ab   = (const float*)d_in[8];
  const float* c3aw   = (const float*)d_in[9];
  const float* c3ab   = (const float*)d_in[10];
  const float* bn1a_s = (const float*)d_in[11];
  const float* bn1a_b = (const float*)d_in[12];
  const float* bn1a_m = (const float*)d_in[13];
  const float* bn1a_v = (const float*)d_in[14];
  const float* bn1b_s = (const float*)d_in[15];
  const float* bn1b_b = (const float*)d_in[16];
  const float* bn1b_m = (const float*)d_in[17];
  const float* bn1b_v = (const float*)d_in[18];
  const float* bn2a_s = (const float*)d_in[19];
  const float* bn2a_b = (const float*)d_in[20];
  const float* bn2a_m = (const float*)d_in[21];
  const float* bn2a_v = (const float*)d_in[22];
  const float* bn3a_s = (const float*)d_in[23];
  const float* bn3a_b = (const float*)d_in[24];
  const float* bn3a_m = (const float*)d_in[25];
  const float* bn3a_v = (const float*)d_in[26];
  const float* fc1w   = (const float*)d_in[27];
  const float* fc1b   = (const float*)d_in[28];
  const float* fc2w   = (const float*)d_in[29];
  const float* fc2b   = (const float*)d_in[30];
  const float* fc3w   = (const float*)d_in[31];
  const float* fc3b   = (const float*)d_in[32];

  // ---- workspace (fl units), peak ~29.6M fl = 118 MB ----
  float* ws = (float*)d_ws;
  float* feat = ws;                                   //   983,040
  _Float16* wt1b = (_Float16*)(ws + 1000000);         //   106,496 h
  _Float16* wt2a = (_Float16*)(ws + 1070000);         //   212,992 h
  _Float16* wt3a = (_Float16*)(ws + 1200000);         //   851,968 h
  float* sc1b = ws + 1700000; float* sh1b = ws + 1700100;
  float* sc2a = ws + 1700200; float* sh2a = ws + 1700400;
  float* sc3a = ws + 1700600; float* sh3a = ws + 1701000;
  _Float16* p1 = (_Float16*)(ws + 1710000);           // 15,728,640 h (full)
  float* S = ws + 9600000;
  float* dct     = S;                                 //  8,388,608 (dead early)
  _Float16* a1c  = (_Float16*)S;                      // 31,457,280 h (64-img chunk)
  _Float16* p2   = (_Float16*)(ws + 25400000);        //  7,864,320 h (full)
  _Float16* p3   = (_Float16*)(ws + 1710000);         //  3,932,160 h (p1 slot)
  float* f1p  = S;                                    // 15,728,640 fl (a1c dead)
  float* f1o  = ws + 29400000;                        //     65,536
  float* f2o  = ws + 29500000;                        //     65,536

  wtrans<64, 64><<<416, 256, 0, stream>>>(c1bw, wt1b);
  wtrans<64, 128><<<832, 256, 0, stream>>>(c2aw, wt2a);
  wtrans<128, 256><<<3328, 256, 0, stream>>>(c3aw, wt3a);
  bnprep<<<1, 256, 0, stream>>>(c1bb, bn1b_s, bn1b_b, bn1b_m, bn1b_v, sc1b, sh1b, 64);
  bnprep<<<1, 256, 0, stream>>>(c2ab, bn2a_s, bn2a_b, bn2a_m, bn2a_v, sc2a, sh2a, 128);
  bnprep<<<1, 256, 0, stream>>>(c3ab, bn3a_s, bn3a_b, bn3a_m, bn3a_v, sc3a, sh3a, 256);

  dct_kernel<<<512, 256, 0, stream>>>(x, basis, dct);
  hist_kernel<<<128 * 64, 256, 0, stream>>>(dct, feat);

  // ---- conv1a + conv1b(MFMA, pooled out) : 2 chunks of 64 images ----
  for (int c = 0; c < 2; ++c) {
    const float* fin = feat + (size_t)c * 64 * 120 * 64;
    _Float16* pout = p1 + (size_t)c * 64 * 8 * 60 * 32 * 8;
    conv1a_f16<<<64 * 30, 256, 0, stream>>>(fin, c1aw, c1ab, bn1a_s, bn1a_b,
                                            bn1a_m, bn1a_v, a1c);
    // TB=15, NCOB=1 -> grid 960
    conv5_mfma<64, 64, 120, 64, 64, false><<<64 * 15, 256, 0, stream>>>(
        a1c, wt1b, sc1b, sh1b, pout);
  }

  // ---- conv2a (full batch, pooled out): TB=4, NCOB=2 -> grid 1024 ----
  conv5_mfma<64, 128, 60, 32, 64, false><<<128 * 4 * 2, 256, 0, stream>>>(
      p1, wt2a, sc2a, sh2a, p2);

  // ---- conv3a (full batch, pooled NCHW out): TB=1, NCOB=4 -> grid 512 ----
  conv5_mfma<128, 256, 30, 16, 64, true><<<128 * 4, 256, 0, stream>>>(
      p2, wt3a, sc3a, sh3a, p3);

  // ---- FC stack ----
  fc1_mfma<<<480, 256, 0, stream>>>(qv, p3, fc1w, f1p);
  fc1_reduce<<<256, 256, 0, stream>>>(f1p, fc1b, f1o);
  fc2_kernel<<<250, 256, 0, stream>>>(qv, f1o, fc2w, fc2b, f2o);
  fc3_kernel<<<1, 256, 0, stream>>>(qv, f2o, fc3w, fc3b, (float*)d_out);
}

// Round 8
// 854.688 us; speedup vs baseline: 1.0822x; 1.0822x over previous
//
#include <hip/hip_runtime.h>

// ============================================================================
// Djpegnet round 8 = round 6 structure + targeted fixes.
//  - conv5_mfma: single-buffered W staging (round-6 flow; round-7 dbuf cost
//    60 extra VGPRs and halved occupancy -> reverted), kw-packed 26-col
//    weights kept (correct in R7; smaller LDS).
//  - conv3a: 256-thr blocks, BLK_M=128, NW_N=2, TB=2 -> grid 512 = 2
//    independent blocks/CU (R6's 256-block grid left 1 block/CU, barriers
//    uncovered). LDS 59.7KB, VGPR ~110.
//  - conv1b/conv2a: round-6 configs (512 thr, grid 512, 2 blocks/CU).
//  - SQ_LDS_BANK_CONFLICT on conv3a identified as fixed shfl-epilogue
//    accounting (~15 cyc/op, HC-independent) -> ignore; HC back to W+4.
//  - Fused BN+ReLU+maxpool epilogues, grouped-f16 acts, fc1 MFMA split-K.
// ============================================================================

typedef _Float16 half8 __attribute__((ext_vector_type(8)));
typedef _Float16 half4 __attribute__((ext_vector_type(4)));
typedef float f32x16 __attribute__((ext_vector_type(16)));

__device__ __forceinline__ void async_copy16(const void* g, void* l) {
  __builtin_amdgcn_global_load_lds(
      (__attribute__((address_space(1))) void*)g,
      (__attribute__((address_space(3))) void*)l, 16, 0, 0);
}

// ---------------------------------------------------------------- DCT ------
__global__ __launch_bounds__(256) void dct_kernel(const float* __restrict__ x,
                                                  const float* __restrict__ basis,
                                                  float* __restrict__ dct) {
  __shared__ __align__(16) float Bm[64];
  int tid = threadIdx.x;
  if (tid < 64) {
    int u = tid >> 3, xx = tid & 7;
    Bm[tid] = basis[(u * 8) * 64 + xx * 8] * 2.8284271247461903f;
  }
  __syncthreads();
  int gid = blockIdx.x * 256 + tid;
  int b = gid >> 10, blk = gid & 1023;
  int bi = blk >> 5, bj = blk & 31;
  const float* xp = x + (size_t)b * 65536 + (bi * 8) * 256 + bj * 8;
  float X[64];
#pragma unroll
  for (int r = 0; r < 8; ++r) {
    float4 p = *(const float4*)(xp + r * 256);
    float4 q = *(const float4*)(xp + r * 256 + 4);
    X[r * 8 + 0] = p.x; X[r * 8 + 1] = p.y; X[r * 8 + 2] = p.z; X[r * 8 + 3] = p.w;
    X[r * 8 + 4] = q.x; X[r * 8 + 5] = q.y; X[r * 8 + 6] = q.z; X[r * 8 + 7] = q.w;
  }
  float T[64];
#pragma unroll
  for (int u = 0; u < 8; ++u) {
    float t[8] = {0.f, 0.f, 0.f, 0.f, 0.f, 0.f, 0.f, 0.f};
#pragma unroll
    for (int xx = 0; xx < 8; ++xx) {
      float bm = Bm[u * 8 + xx];
#pragma unroll
      for (int y = 0; y < 8; ++y) t[y] += bm * X[xx * 8 + y];
    }
#pragma unroll
    for (int y = 0; y < 8; ++y) T[u * 8 + y] = t[y];
  }
  float* op = dct + (size_t)b * 65536 + bi * 32 + bj;
#pragma unroll
  for (int v = 0; v < 8; ++v) {
    float dc[8] = {0.f, 0.f, 0.f, 0.f, 0.f, 0.f, 0.f, 0.f};
#pragma unroll
    for (int y = 0; y < 8; ++y) {
      float bm = Bm[v * 8 + y];
#pragma unroll
      for (int u = 0; u < 8; ++u) dc[u] += bm * T[u * 8 + y];
    }
#pragma unroll
    for (int u = 0; u < 8; ++u) op[(u * 8 + v) * 1024] = dc[u];
  }
}

// ---------------------------------------------------- soft histogram -------
__global__ __launch_bounds__(256) void hist_kernel(const float* __restrict__ dct,
                                                   float* __restrict__ feat) {
  __shared__ __align__(16) float h[16 * 121];
  int tid = threadIdx.x;
  for (int i = tid; i < 16 * 121; i += 256) h[i] = 0.f;
  __syncthreads();
  int b = blockIdx.x >> 6, c = blockIdx.x & 63;
  const float* dp = dct + (size_t)(b * 64 + c) * 1024;
  float* hc = h + (tid & 15) * 121;
  float4 v4 = ((const float4*)dp)[tid];
  float vals[4] = {v4.x, v4.y, v4.z, v4.w};
#pragma unroll
  for (int i = 0; i < 4; ++i) {
    float d = vals[i];
    float fl = floorf(d);
    float t0 = d - fl;
    int k = (int)fl + 60;
    if (t0 >= 2e-5f && t0 <= 1.f - 1.2e-4f) {
      if (k >= 0 && k < 120) atomicAdd(hc + k, 1.0f);
    } else {
      float s0 = 1.f / (1.f + expf(-1e6f * t0));
      float s1 = 1.f / (1.f + expf(1e6f * (1.f - t0)));
      if (k >= 1 && k <= 120) atomicAdd(hc + k - 1, 1.f - s0);
      if (k >= 0 && k < 120)  atomicAdd(hc + k, s0 - s1);
      if (k >= -1 && k < 119) atomicAdd(hc + k + 1, s1);
    }
  }
  __syncthreads();
  for (int f = tid; f < 120; f += 256) {
    float s = 0.f;
#pragma unroll
    for (int l = 0; l < 16; ++l) s += h[l * 121 + f];
    feat[((size_t)b * 120 + f) * 64 + c] = s * (1.f / 1024.f);
  }
}

// ---------------------------------------- weight transpose + BN folding ----
// wt layout: [cg][26][co][8ci], col = kh*5+kw (kw 0..4); col 25 = zeros.
template <int CI, int CO>
__global__ __launch_bounds__(256) void wtrans(const float* __restrict__ w,
                                              _Float16* __restrict__ wt) {
  int i = blockIdx.x * 256 + threadIdx.x;
  if (i >= (CI / 8) * 26 * CO * 8) return;
  int c8 = i & 7;
  int t = i >> 3;
  int co = t % CO; t /= CO;
  int k = t % 26;
  int cg = t / 26;
  float v = 0.f;
  if (k < 25) {
    int kh = k / 5, kw = k % 5;
    v = w[((size_t)co * CI + cg * 8 + c8) * 25 + kh * 5 + kw];
  }
  wt[i] = (_Float16)v;
}

__global__ __launch_bounds__(256) void bnprep(const float* __restrict__ cb,
                                              const float* __restrict__ s,
                                              const float* __restrict__ b,
                                              const float* __restrict__ m,
                                              const float* __restrict__ v,
                                              float* __restrict__ scale,
                                              float* __restrict__ shift, int n) {
  int i = threadIdx.x;
  if (i < n) {
    float inv = s[i] * rsqrtf(v[i] + 1e-5f);
    scale[i] = inv;
    shift[i] = (cb[i] - m[i]) * inv + b[i];
  }
}

// -------------------------- conv1a: fp32 direct, out grouped-NHWC f16 ------
__global__ __launch_bounds__(256) void conv1a_f16(
    const float* __restrict__ in, const float* __restrict__ wts,
    const float* __restrict__ cb, const float* __restrict__ s_,
    const float* __restrict__ b_, const float* __restrict__ m_,
    const float* __restrict__ v_, _Float16* __restrict__ out) {
  __shared__ __align__(16) float wl[5 * 8 * 20];
  __shared__ __align__(16) float il[12 * 68];
  int tid = threadIdx.x, bid = blockIdx.x;
  int img = bid / 30;
  int r = bid % 30;
  int cob = r / 15;
  int h0 = (r % 15) * 8;
  int cog = tid & 7, wg = (tid >> 3) & 3, hh = tid >> 5;
  float acc[4][16];
#pragma unroll
  for (int i = 0; i < 4; ++i)
#pragma unroll
    for (int j = 0; j < 16; ++j) acc[i][j] = 0.f;
  for (int idx = tid; idx < 32 * 25; idx += 256) {
    int rr = idx % 25, co = idx / 25;
    float v = wts[(cob * 32 + co) * 25 + rr];
    int kh = rr / 5, kw = rr % 5;
    wl[(kh * 8 + (co >> 2)) * 20 + (co & 3) * 5 + kw] = v;
  }
  for (int idx = tid; idx < 12 * 68; idx += 256) {
    int cc = idx % 68, rr = idx / 68;
    int hy = h0 + rr - 2, wx = cc - 2;
    float v = 0.f;
    if (hy >= 0 && hy < 120 && wx >= 0 && wx < 64)
      v = in[(size_t)img * 7680 + hy * 64 + wx];
    il[idx] = v;
  }
  __syncthreads();
#pragma unroll
  for (int kh = 0; kh < 5; ++kh) {
    const float* ir = &il[(hh + kh) * 68 + wg * 16];
    float iv[20];
#pragma unroll
    for (int i = 0; i < 5; ++i) {
      float4 p = *(const float4*)(ir + i * 4);
      iv[i * 4] = p.x; iv[i * 4 + 1] = p.y; iv[i * 4 + 2] = p.z; iv[i * 4 + 3] = p.w;
    }
    const float* wr = &wl[(kh * 8 + cog) * 20];
    float wv[20];
#pragma unroll
    for (int i = 0; i < 5; ++i) {
      float4 p = *(const float4*)(wr + i * 4);
      wv[i * 4] = p.x; wv[i * 4 + 1] = p.y; wv[i * 4 + 2] = p.z; wv[i * 4 + 3] = p.w;
    }
#pragma unroll
    for (int co = 0; co < 4; ++co)
#pragma unroll
      for (int kw = 0; kw < 5; ++kw) {
        float w1 = wv[co * 5 + kw];
#pragma unroll
        for (int w = 0; w < 16; ++w) acc[co][w] += w1 * iv[w + kw];
      }
  }
  int h = h0 + hh;
  int co0 = cob * 32 + cog * 4;
  float inv[4], bia[4];
#pragma unroll
  for (int i = 0; i < 4; ++i) {
    int c = co0 + i;
    inv[i] = s_[c] * rsqrtf(v_[c] + 1e-5f);
    bia[i] = (cb[c] - m_[c]) * inv[i] + b_[c];
  }
  int g = co0 >> 3, off = co0 & 7;
  _Float16* op = out + (((size_t)(img * 8 + g) * 120 + h) * 64) * 8 + off;
#pragma unroll
  for (int w = 0; w < 16; ++w) {
    half4 o;
#pragma unroll
    for (int i = 0; i < 4; ++i)
      o[i] = (_Float16)fmaxf(acc[i][w] * inv[i] + bia[i], 0.f);
    *(half4*)&op[(size_t)(wg * 16 + w) * 8] = o;
  }
}

// ------ MFMA implicit-GEMM 5x5 conv + BN + ReLU + maxpool2 (fused) ---------
// THREADS = 256 or 512. Single-buffered W staging via async global_load_lds.
// Output pooled: grouped [img][CO/8][H/2][W/2][8] or NCHW [img][CO][H/2][W/2].
template <int THREADS, int CI, int CO, int H, int W, int BLK_M, bool OUT_NCHW>
__global__ __launch_bounds__(THREADS) void conv5_mfma(
    const _Float16* __restrict__ in, const _Float16* __restrict__ wt,
    const float* __restrict__ scale, const float* __restrict__ shift,
    _Float16* __restrict__ out) {
  constexpr int NW = THREADS / 64;
  constexpr int NW_M = BLK_M / 64;
  constexpr int NW_N = NW / NW_M;
  constexpr int BLK_N = NW_N * 128;
  constexpr int ROWS = BLK_N / W;
  constexpr int TB = (H + ROWS - 1) / ROWS;
  constexpr int NCOB = CO / BLK_M;
  constexpr int HR = ROWS + 4;
  constexpr int HC = W + 4;
  constexpr int CIG = CI / 8;
  constexpr int OH = H / 2, OW = W / 2;
  constexpr int AITER = (HR * HC + THREADS - 1) / THREADS;
  constexpr int KCOLS = 26;                  // kh*5+kw packed, col 25 = zeros
  constexpr int WBYTES = KCOLS * BLK_M * 16;
  constexpr int WITER = (WBYTES + THREADS * 16 - 1) / (THREADS * 16);
  constexpr int RB = BLK_M * 16;             // bytes per tap column
  __shared__ __align__(16) _Float16 Alds[HR * HC * 8 + 8];
  __shared__ __align__(16) _Float16 Wlds[KCOLS * BLK_M * 8];

  int tid = threadIdx.x;
  int bid = blockIdx.x;
  int img = bid / (TB * NCOB);
  int r = bid % (TB * NCOB);
  int tb = r / NCOB;
  int cob = r % NCOB;
  int h0 = tb * ROWS;

  int wid = tid >> 6, l = tid & 63, lo = l & 31, hi = l >> 5;
  int widM = wid / NW_N, widN = wid % NW_N;

  if (tid < 8) Alds[HR * HC * 8 + tid] = (_Float16)0.f;  // zero read-slack

  int wbase[2];
#pragma unroll
  for (int mi = 0; mi < 2; ++mi)
    wbase[mi] = (hi * BLK_M + widM * 64 + mi * 32 + lo) * 8;
  int bbase[4];
#pragma unroll
  for (int j = 0; j < 4; ++j) {
    int pix = widN * 128 + j * 32 + lo;
    bbase[j] = ((pix / W) * HC + (pix % W) + hi) * 8;
  }

  f32x16 acc[2][4];
#pragma unroll
  for (int mi = 0; mi < 2; ++mi)
#pragma unroll
    for (int j = 0; j < 4; ++j) acc[mi][j] = (f32x16){};

#pragma unroll 1
  for (int cg = 0; cg < CIG; ++cg) {
    const _Float16* ing = in + (size_t)(img * CIG + cg) * H * W * 8;
    // A loads into regs first (oldest in vmcnt queue)
    half8 areg[AITER];
#pragma unroll
    for (int it = 0; it < AITER; ++it) {
      int i = tid + it * THREADS;
      half8 v = {};
      if (i < HR * HC) {
        int rr2 = i / HC, cc = i % HC;
        int hy = h0 + rr2 - 2, wx = cc - 2;
        if (hy >= 0 && hy < H && wx >= 0 && wx < W)
          v = *(const half8*)&ing[(size_t)(hy * W + wx) * 8];
      }
      areg[it] = v;
    }
    // W: async direct-to-LDS memcpy
    const char* wsrc = (const char*)(wt + ((size_t)cg * KCOLS * CO + cob * BLK_M) * 8);
#pragma unroll
    for (int rr2 = 0; rr2 < WITER; ++rr2) {
      int f = rr2 * (THREADS * 16) + tid * 16;
      if (f < WBYTES) {
        int row = f / RB;
        int off = f % RB;
        async_copy16(wsrc + (size_t)row * (CO * 16) + off,
                     (char*)Wlds + rr2 * (THREADS * 16) + wid * 1024);
      }
    }
    // A writes to LDS
#pragma unroll
    for (int it = 0; it < AITER; ++it) {
      int i = tid + it * THREADS;
      if (i < HR * HC) *(half8*)&Alds[i * 8] = areg[it];
    }
    __syncthreads();
#pragma unroll
    for (int kh = 0; kh < 5; ++kh) {
#pragma unroll
      for (int kwb = 0; kwb < 3; ++kwb) {
        half8 af[2], bf[4];
#pragma unroll
        for (int mi = 0; mi < 2; ++mi) {
          af[mi] = *(const half8*)&Wlds[wbase[mi] + (kh * 5 + 2 * kwb) * BLK_M * 8];
          if (kwb == 2) af[mi] = hi ? (half8){} : af[mi];  // packed kw=5 tap
        }
#pragma unroll
        for (int j = 0; j < 4; ++j)
          bf[j] = *(const half8*)&Alds[bbase[j] + (kh * HC + 2 * kwb) * 8];
#pragma unroll
        for (int mi = 0; mi < 2; ++mi)
#pragma unroll
          for (int j = 0; j < 4; ++j)
            acc[mi][j] = __builtin_amdgcn_mfma_f32_32x32x16_f16(
                af[mi], bf[j], acc[mi][j], 0, 0, 0);
      }
    }
    __syncthreads();
  }

  // ---- fused BN + ReLU + 2x2 maxpool epilogue ----
  if (!OUT_NCHW) {
    constexpr int CGO = CO / 8;
    int gbase = (cob * BLK_M + widM * 64) >> 3;
    bool lane_ok = ((lo & 1) == 0);
#pragma unroll
    for (int mi = 0; mi < 2; ++mi) {
#pragma unroll
      for (int r4 = 0; r4 < 4; ++r4) {
        int g = gbase + mi * 4 + r4;
        int co0 = g * 8 + hi * 4;
        float4 sv = *(const float4*)&scale[co0];
        float4 tv = *(const float4*)&shift[co0];
        float sa[4] = {sv.x, sv.y, sv.z, sv.w};
        float ta[4] = {tv.x, tv.y, tv.z, tv.w};
#pragma unroll
        for (int pp = 0; pp < 2; ++pp) {
          int ja = (W == 64) ? pp : 2 * pp;
          int jb = (W == 64) ? pp + 2 : 2 * pp + 1;
          int orow = (W == 64) ? (h0 >> 1) + widN : (h0 >> 1) + widN * 2 + pp;
          int ocol = (W == 64) ? pp * 16 + (lo >> 1) : (lo >> 1);
          half4 o;
#pragma unroll
          for (int c = 0; c < 4; ++c) {
            int reg = r4 * 4 + c;
            float v0 = fmaxf(acc[mi][ja][reg] * sa[c] + ta[c], 0.f);
            float v1 = fmaxf(acc[mi][jb][reg] * sa[c] + ta[c], 0.f);
            float m = fmaxf(v0, v1);
            m = fmaxf(m, __shfl_xor(m, 1, 64));
            o[c] = (_Float16)m;
          }
          if (lane_ok && orow < OH)
            *(half4*)&out[(((size_t)(img * CGO + g) * OH + orow) * OW + ocol) * 8 +
                          hi * 4] = o;
        }
      }
    }
  } else {
    bool lane_ok = ((lo & 1) == 0) && (lo < 16);
#pragma unroll
    for (int mi = 0; mi < 2; ++mi) {
#pragma unroll
      for (int reg = 0; reg < 16; ++reg) {
        int co = cob * BLK_M + widM * 64 + mi * 32 + (reg & 3) + 8 * (reg >> 2) + 4 * hi;
        float s = scale[co], t = shift[co];
#pragma unroll
        for (int j = 0; j < 4; ++j) {
          float v = fmaxf(acc[mi][j][reg] * s + t, 0.f);
          float m = fmaxf(v, __shfl_xor(v, 16, 64));
          m = fmaxf(m, __shfl_xor(m, 1, 64));
          int orow = (h0 >> 1) + widN * 4 + j;
          if (lane_ok && orow < OH)
            out[((size_t)(img * CO + co) * OH + orow) * OW + ((lo & 15) >> 1)] =
                (_Float16)m;
        }
      }
    }
  }
}

// --------------------------------------------------- fc1: f16 MFMA split-K -
__global__ __launch_bounds__(256, 2) void fc1_mfma(const float* __restrict__ qv,
                                                   const _Float16* __restrict__ p3,
                                                   const float* __restrict__ w,
                                                   float* __restrict__ part) {
  __shared__ __align__(16) _Float16 Wl[8 * 256 * 8];
  __shared__ __align__(16) _Float16 Bl[8 * 128 * 8];
  int tid = threadIdx.x;
  int ks = blockIdx.x >> 1, mt = blockIdx.x & 1;
  int wid = tid >> 6, l = tid & 63, lo = l & 31, hi = l >> 5;
  f32x16 acc[2][4];
#pragma unroll
  for (int mi = 0; mi < 2; ++mi)
#pragma unroll
    for (int j = 0; j < 4; ++j) acc[mi][j] = (f32x16){};

#pragma unroll 1
  for (int i3 = 0; i3 < 3; ++i3) {
    int c = ks + 240 * i3;
    if (c > 480) break;
    for (int idx = tid; idx < 2048; idx += 256) {
      int n_loc = idx >> 3, k8 = idx & 7;
      int n = mt * 256 + n_loc;
      half8 v = {};
      if (n < 500) {
        const float* src = w + (size_t)n * 30784 + c * 64 + k8 * 8;
        float4 f0 = *(const float4*)src;
        float4 f1 = *(const float4*)(src + 4);
        v[0] = (_Float16)f0.x; v[1] = (_Float16)f0.y;
        v[2] = (_Float16)f0.z; v[3] = (_Float16)f0.w;
        v[4] = (_Float16)f1.x; v[5] = (_Float16)f1.y;
        v[6] = (_Float16)f1.z; v[7] = (_Float16)f1.w;
      }
      *(half8*)&Wl[(size_t)(k8 * 256 + n_loc) * 8] = v;
    }
    for (int idx = tid; idx < 1024; idx += 256) {
      int img = idx >> 3, k8 = idx & 7;
      half8 v;
      if (c == 0) {
        const float* src = qv + img * 64 + k8 * 8;
        float4 f0 = *(const float4*)src;
        float4 f1 = *(const float4*)(src + 4);
        v[0] = (_Float16)f0.x; v[1] = (_Float16)f0.y;
        v[2] = (_Float16)f0.z; v[3] = (_Float16)f0.w;
        v[4] = (_Float16)f1.x; v[5] = (_Float16)f1.y;
        v[6] = (_Float16)f1.z; v[7] = (_Float16)f1.w;
      } else {
        v = *(const half8*)&p3[(size_t)img * 30720 + (c * 64 - 64) + k8 * 8];
      }
      *(half8*)&Bl[(size_t)(k8 * 128 + img) * 8] = v;
    }
    __syncthreads();
#pragma unroll
    for (int ks16 = 0; ks16 < 4; ++ks16) {
      half8 af[2], bf[4];
#pragma unroll
      for (int mi = 0; mi < 2; ++mi)
        af[mi] = *(const half8*)&Wl[(size_t)((ks16 * 2 + hi) * 256 + wid * 64 +
                                             mi * 32 + lo) * 8];
#pragma unroll
      for (int j = 0; j < 4; ++j)
        bf[j] = *(const half8*)&Bl[(size_t)((ks16 * 2 + hi) * 128 + j * 32 + lo) * 8];
#pragma unroll
      for (int mi = 0; mi < 2; ++mi)
#pragma unroll
        for (int j = 0; j < 4; ++j)
          acc[mi][j] = __builtin_amdgcn_mfma_f32_32x32x16_f16(
              af[mi], bf[j], acc[mi][j], 0, 0, 0);
    }
    __syncthreads();
  }
#pragma unroll
  for (int mi = 0; mi < 2; ++mi)
#pragma unroll
    for (int reg = 0; reg < 16; ++reg) {
      int n = mt * 256 + wid * 64 + mi * 32 + (reg & 3) + 8 * (reg >> 2) + 4 * hi;
#pragma unroll
      for (int j = 0; j < 4; ++j)
        part[((size_t)ks * 512 + n) * 128 + j * 32 + lo] = acc[mi][j][reg];
    }
}

__global__ __launch_bounds__(256) void fc1_reduce(const float* __restrict__ part,
                                                  const float* __restrict__ bias,
                                                  float* __restrict__ out) {
  int idx = blockIdx.x * 256 + threadIdx.x;
  int img = idx & 127, n = idx >> 7;
  float s = 0.f;
#pragma unroll 8
  for (int ks = 0; ks < 240; ++ks) s += part[((size_t)ks * 512 + n) * 128 + img];
  out[n * 128 + img] = (n < 500) ? fmaxf(s + bias[n], 0.f) : 0.f;
}

// -------------------------------------------------------- fc2 / fc3 --------
__global__ __launch_bounds__(256) void fc2_kernel(const float* __restrict__ qv,
                                                  const float* __restrict__ fc1o,
                                                  const float* __restrict__ w,
                                                  const float* __restrict__ bias,
                                                  float* __restrict__ out) {
  int idx = blockIdx.x * 256 + threadIdx.x;
  if (idx >= 128 * 500) return;
  int m = idx & 127, n = idx >> 7;
  const float* wr = w + (size_t)n * 564;
  float acc = 0.f;
#pragma unroll 8
  for (int k = 0; k < 64; ++k) acc += qv[m * 64 + k] * wr[k];
#pragma unroll 4
  for (int k = 0; k < 500; ++k) acc += fc1o[k * 128 + m] * wr[64 + k];
  out[n * 128 + m] = fmaxf(acc + bias[n], 0.f);
}

__global__ __launch_bounds__(256) void fc3_kernel(const float* __restrict__ qv,
                                                  const float* __restrict__ fc2o,
                                                  const float* __restrict__ w,
                                                  const float* __restrict__ bias,
                                                  float* __restrict__ out) {
  int tid = threadIdx.x;
  int m = tid >> 1, n = tid & 1;
  const float* wr = w + (size_t)n * 564;
  float acc = 0.f;
#pragma unroll 8
  for (int k = 0; k < 64; ++k) acc += qv[m * 64 + k] * wr[k];
#pragma unroll 4
  for (int k = 0; k < 500; ++k) acc += fc2o[k * 128 + m] * wr[64 + k];
  out[m * 2 + n] = acc + bias[n];
}

// ----------------------------------------------------------- launcher ------
extern "C" void kernel_launch(void* const* d_in, const int* in_sizes, int n_in,
                              void* d_out, int out_size, void* d_ws, size_t ws_size,
                              hipStream_t stream) {
  (void)in_sizes; (void)n_in; (void)out_size; (void)ws_size;
  const float* x      = (const float*)d_in[0];
  const float* qv     = (const float*)d_in[1];
  const float* basis  = (const float*)d_in[2];
  const float* c1aw   = (const float*)d_in[3];
  const float* c1ab   = (const float*)d_in[4];
  const float* c1bw   = (const float*)d_in[5];
  const float* c1bb   = (const float*)d_in[6];
  const float* c2aw   = (const float*)d_in[7];
  const float* c2ab   = (const float*)d_in[8];
  const float* c3aw   = (const float*)d_in[9];
  const float* c3ab   = (const float*)d_in[10];
  const float* bn1a_s = (const float*)d_in[11];
  const float* bn1a_b = (const float*)d_in[12];
  const float* bn1a_m = (const float*)d_in[13];
  const float* bn1a_v = (const float*)d_in[14];
  const float* bn1b_s = (const float*)d_in[15];
  const float* bn1b_b = (const float*)d_in[16];
  const float* bn1b_m = (const float*)d_in[17];
  const float* bn1b_v = (const float*)d_in[18];
  const float* bn2a_s = (const float*)d_in[19];
  const float* bn2a_b = (const float*)d_in[20];
  const float* bn2a_m = (const float*)d_in[21];
  const float* bn2a_v = (const float*)d_in[22];
  const float* bn3a_s = (const float*)d_in[23];
  const float* bn3a_b = (const float*)d_in[24];
  const float* bn3a_m = (const float*)d_in[25];
  const float* bn3a_v = (const float*)d_in[26];
  const float* fc1w   = (const float*)d_in[27];
  const float* fc1b   = (const float*)d_in[28];
  const float* fc2w   = (const float*)d_in[29];
  const float* fc2b   = (const float*)d_in[30];
  const float* fc3w   = (const float*)d_in[31];
  const float* fc3b   = (const float*)d_in[32];

  // ---- workspace (fl units), peak ~29.6M fl = 118 MB ----
  float* ws = (float*)d_ws;
  float* feat = ws;                                   //   983,040
  _Float16* wt1b = (_Float16*)(ws + 1000000);         //   106,496 h
  _Float16* wt2a = (_Float16*)(ws + 1070000);         //   212,992 h
  _Float16* wt3a = (_Float16*)(ws + 1200000);         //   851,968 h
  float* sc1b = ws + 1700000; float* sh1b = ws + 1700100;
  float* sc2a = ws + 1700200; float* sh2a = ws + 1700400;
  float* sc3a = ws + 1700600; float* sh3a = ws + 1701000;
  _Float16* p1 = (_Float16*)(ws + 1710000);           // 15,728,640 h (full)
  float* S = ws + 9600000;
  float* dct     = S;                                 //  8,388,608 (dead early)
  _Float16* a1c  = (_Float16*)S;                      // 31,457,280 h (64-img chunk)
  _Float16* p2   = (_Float16*)(ws + 25400000);        //  7,864,320 h (full)
  _Float16* p3   = (_Float16*)(ws + 1710000);         //  3,932,160 h (p1 slot)
  float* f1p  = S;                                    // 15,728,640 fl (a1c dead)
  float* f1o  = ws + 29400000;                        //     65,536
  float* f2o  = ws + 29500000;                        //     65,536

  wtrans<64, 64><<<416, 256, 0, stream>>>(c1bw, wt1b);
  wtrans<64, 128><<<832, 256, 0, stream>>>(c2aw, wt2a);
  wtrans<128, 256><<<3328, 256, 0, stream>>>(c3aw, wt3a);
  bnprep<<<1, 256, 0, stream>>>(c1bb, bn1b_s, bn1b_b, bn1b_m, bn1b_v, sc1b, sh1b, 64);
  bnprep<<<1, 256, 0, stream>>>(c2ab, bn2a_s, bn2a_b, bn2a_m, bn2a_v, sc2a, sh2a, 128);
  bnprep<<<1, 256, 0, stream>>>(c3ab, bn3a_s, bn3a_b, bn3a_m, bn3a_v, sc3a, sh3a, 256);

  dct_kernel<<<512, 256, 0, stream>>>(x, basis, dct);
  hist_kernel<<<128 * 64, 256, 0, stream>>>(dct, feat);

  // ---- conv1a + conv1b(MFMA, pooled out): 2 chunks of 64 images ----
  for (int c = 0; c < 2; ++c) {
    const float* fin = feat + (size_t)c * 64 * 120 * 64;
    _Float16* pout = p1 + (size_t)c * 64 * 8 * 60 * 32 * 8;
    conv1a_f16<<<64 * 30, 256, 0, stream>>>(fin, c1aw, c1ab, bn1a_s, bn1a_b,
                                            bn1a_m, bn1a_v, a1c);
    // 512 thr, BLK_M=64, NW_N=8, ROWS=16, TB=8 -> grid 512 (2 blocks/CU)
    conv5_mfma<512, 64, 64, 120, 64, 64, false><<<64 * 8, 512, 0, stream>>>(
        a1c, wt1b, sc1b, sh1b, pout);
  }

  // ---- conv2a: 512 thr, BLK_M=128, NW_N=4, ROWS=16, TB=4 -> grid 512 ----
  conv5_mfma<512, 64, 128, 60, 32, 128, false><<<128 * 4, 512, 0, stream>>>(
      p1, wt2a, sc2a, sh2a, p2);

  // ---- conv3a: 256 thr, BLK_M=128, NW_N=2, ROWS=16, TB=2, NCOB=2 -> 512 ----
  conv5_mfma<256, 128, 256, 30, 16, 128, true><<<128 * 2 * 2, 256, 0, stream>>>(
      p2, wt3a, sc3a, sh3a, p3);

  // ---- FC stack ----
  fc1_mfma<<<480, 256, 0, stream>>>(qv, p3, fc1w, f1p);
  fc1_reduce<<<256, 256, 0, stream>>>(f1p, fc1b, f1o);
  fc2_kernel<<<250, 256, 0, stream>>>(qv, f1o, fc2w, fc2b, f2o);
  fc3_kernel<<<1, 256, 0, stream>>>(qv, f2o, fc3w, fc3b, (float*)d_out);
}